// Round 5
// baseline (654.630 us; speedup 1.0000x reference)
//
#include <hip/hip_runtime.h>
#include <hip/hip_bf16.h>
#include <stdint.h>

typedef __attribute__((ext_vector_type(8))) short short8;
typedef __attribute__((ext_vector_type(4))) float f32x4;
typedef __attribute__((ext_vector_type(4))) unsigned int u32x4;

#define NROWS 32768
#define DIM 512
#define KTOT 8192
#define KSPL 7680
#define LNEPS 1e-3f
// q = SQL * xn ; basis = exp2(-(q - SQL*grid_g)^2) ; SQL = 3.5*sqrt(log2(e))
#define SQL 4.20392843f

#if __has_builtin(__builtin_amdgcn_exp2f)
#define EXP2F(x) __builtin_amdgcn_exp2f(x)
#else
#define EXP2F(x) exp2f(x)
#endif

__device__ __forceinline__ unsigned short f2bf(float f) {
    unsigned u = __float_as_uint(f);
    u += 0x7fffu + ((u >> 16) & 1u);           // RNE
    return (unsigned short)(u >> 16);
}

// pack two floats -> two bf16 (round-half-up) in one u32 via v_perm
__device__ __forceinline__ unsigned pack_bf2(float a, float b) {
    unsigned ua = __float_as_uint(a) + 0x8000u;
    unsigned ub = __float_as_uint(b) + 0x8000u;
    return __builtin_amdgcn_perm(ub, ua, 0x07060302u); // lo16=ua>>16, hi16=ub>>16
}

// ---------------- prep: weights -> bf16 Bw[o][k], k = g*512+d (spline) | 7680+d (base^T)
// Coalesced global reads AND writes; transpose goes through LDS (stride-15
// float reads -> conflict-free on 32 banks).
__global__ __launch_bounds__(256) void prep_w_k(const float* __restrict__ sw,
                                                const float* __restrict__ bwt,
                                                unsigned short* __restrict__ Bw) {
    __shared__ float lds[KSPL];
    const int o = blockIdx.x;
    const int t = threadIdx.x;
    const float* swr = sw + (size_t)o * KSPL;
    unsigned short* br = Bw + (size_t)o * KTOT;
    #pragma unroll
    for (int it = 0; it < 30; ++it) lds[it * 256 + t] = swr[it * 256 + t];
    #pragma unroll
    for (int it = 0; it < 2; ++it) {
        int d = it * 256 + t;
        br[KSPL + d] = f2bf(bwt[(size_t)d * DIM + o]);
    }
    __syncthreads();
    #pragma unroll
    for (int it = 0; it < 30; ++it) {
        int k = it * 256 + t;              // destination order: k = g*512 + d
        int g = k >> 9, d = k & 511;
        br[k] = f2bf(lds[d * 15 + g]);
    }
}

// ---------------- fused LN + KAN GEMM: out[n][o] = sum_k A[n][k]*Bw[o][k] + bb[o]
// A generated on the fly (k<7680: RBF basis of LN(x); else relu(x)), staged in
// double-buffered LDS (2x16KB, 8x inter-wave reuse). B is NOT staged: each
// lane global_load_dwordx4's its 16B fragment straight from L2 (fully
// coalesced: 4 fq-lanes fill each 64B line; per-step slice is L2-resident,
// Bw is L3-resident). => no global_load_lds, no vmcnt(0) drain cost, ONE
// __syncthreads per k-step; compiler free-schedules B-issue/A-ds_read/MFMA/
// next-step-basis-VALU inside each step. Block 128x512, 16 waves, grid 256.
__global__ __launch_bounds__(1024, 4) void kan_gemm(
    const float* __restrict__ x,
    const unsigned short* __restrict__ Bw,
    const float* __restrict__ gam,
    const float* __restrict__ bet,
    const float* __restrict__ bb,
    float* __restrict__ out) {
    __shared__ __align__(16) short As[2][128 * 64];      // 32 KB total

    const int t = threadIdx.x;
    const int w = t >> 6, l = t & 63;
    const int n0 = blockIdx.x << 7;

    const int ar  = t >> 3;    // A-staging row 0..127 (also LN-stats row)
    const int kkg = t & 7;     // A-staging k-granule
    const int wm = (w >> 3) << 6;            // wave row offset: 0 / 64
    const int wn = (w & 7) << 6;             // wave col offset: 0..448
    const int fm = l & 15, fq = l >> 4;
    const int asto = ((ar << 3) | (kkg ^ (ar & 7))) << 3;  // As store short-index

    // per-lane B element-offsets: row (out-col) n, k-granule fq (ks adds 32)
    int voffB[4];
    #pragma unroll
    for (int nt = 0; nt < 4; ++nt)
        voffB[nt] = (wn + (nt << 4) + fm) * KTOT + (fq << 3);

    // ---- LayerNorm stats for row ar (8 threads/row, shuffle reduce)
    const float* xrow = x + (size_t)(n0 + ar) * DIM;
    float s = 0.f, ss = 0.f;
    #pragma unroll
    for (int it = 0; it < 16; ++it) {
        float4 v = *(const float4*)(xrow + it * 32 + ((t & 7) << 2));
        s  += v.x + v.y + v.z + v.w;
        ss += v.x * v.x + v.y * v.y + v.z * v.z + v.w * v.w;
    }
    #pragma unroll
    for (int m = 4; m >= 1; m >>= 1) {
        s  += __shfl_xor(s,  m, 64);
        ss += __shfl_xor(ss, m, 64);
    }
    const float mean = s * (1.0f / DIM);
    const float rstd = rsqrtf(ss * (1.0f / DIM) - mean * mean + LNEPS);
    const float sr = SQL * rstd;

    f32x4 acc[4][4];
    #pragma unroll
    for (int i = 0; i < 4; ++i)
        #pragma unroll
        for (int j = 0; j < 4; ++j)
            acc[i][j] = (f32x4)0.0f;

    float q[8];   // pre-scaled SQL*layernorm(x) for current d-block (carried)

    auto loadq = [&](int dn) {
        const int dc = (dn << 6) + (kkg << 3);
        float4 a = *(const float4*)(xrow + dc);
        float4 b = *(const float4*)(xrow + dc + 4);
        float xv[8] = {a.x, a.y, a.z, a.w, b.x, b.y, b.z, b.w};
        float4 g0 = *(const float4*)(gam + dc);
        float4 g1 = *(const float4*)(gam + dc + 4);
        float4 b0 = *(const float4*)(bet + dc);
        float4 b1 = *(const float4*)(bet + dc + 4);
        float gv[8] = {g0.x, g0.y, g0.z, g0.w, g1.x, g1.y, g1.z, g1.w};
        float bv[8] = {b0.x, b0.y, b0.z, b0.w, b1.x, b1.y, b1.z, b1.w};
        #pragma unroll
        for (int j = 0; j < 8; ++j) {
            float c = sr * gv[j];
            float o = __builtin_fmaf(-mean, c, SQL * bv[j]);
            q[j] = __builtin_fmaf(xv[j], c, o);
        }
    };

    // basis (gp<15) or relu (gp==15, x reloaded: L3-hit, 1x per 16 steps)
    auto stageA = [&](int nb, int gp, int dn) {
        u32x4 v;
        if (gp < 15) {
            const float qg = SQL * (-2.0f + (float)gp * (2.0f / 7.0f));
            float e[8];
            #pragma unroll
            for (int j = 0; j < 8; ++j) {
                float d = q[j] - qg;
                e[j] = EXP2F(-(d * d));
            }
            v[0] = pack_bf2(e[0], e[1]);
            v[1] = pack_bf2(e[2], e[3]);
            v[2] = pack_bf2(e[4], e[5]);
            v[3] = pack_bf2(e[6], e[7]);
        } else {
            const int dc = (dn << 6) + (kkg << 3);
            float4 a = *(const float4*)(xrow + dc);
            float4 b = *(const float4*)(xrow + dc + 4);
            v[0] = pack_bf2(fmaxf(a.x, 0.f), fmaxf(a.y, 0.f));
            v[1] = pack_bf2(fmaxf(a.z, 0.f), fmaxf(a.w, 0.f));
            v[2] = pack_bf2(fmaxf(b.x, 0.f), fmaxf(b.y, 0.f));
            v[3] = pack_bf2(fmaxf(b.z, 0.f), fmaxf(b.w, 0.f));
        }
        *(u32x4*)&As[nb][asto] = v;
    };

    // ---- prologue: stage step 0's A into buffer 0
    loadq(0);
    stageA(0, 0, 0);
    __syncthreads();

    #pragma unroll 1
    for (int sp = 0; sp < 128; ++sp) {
        const int c = sp & 1;
        const int g = sp & 15, dsb = sp >> 4;
        const int kc = (g < 15) ? ((g << 9) + (dsb << 6)) : (KSPL + (dsb << 6));
        // ---- stage next step's A into the other buffer (VALU+ds_write,
        // free to interleave with this step's B loads / ds_reads / MFMAs)
        const int snx = sp + 1;
        if (snx < 128) {
            const int g1 = snx & 15, d1 = snx >> 4;
            if (g1 == 0) loadq(d1);        // uniform branch, 7x per kernel
            stageA(c ^ 1, g1, d1);
        }
        // ---- MFMA: B-frags direct from global (L2), A-frags from LDS
        const unsigned short* bbase = Bw + kc;   // kc uniform -> SGPR base
        const short* Asc = &As[c][0];
        #pragma unroll
        for (int ks = 0; ks < 2; ++ks) {
            short8 bfr[4];
            #pragma unroll
            for (int nt = 0; nt < 4; ++nt)
                bfr[nt] = *(const short8*)(bbase + voffB[nt] + (ks << 5));
            const int kg = (ks << 2) + fq;
            short8 af[4];
            #pragma unroll
            for (int mt = 0; mt < 4; ++mt) {
                const int m = wm + (mt << 4) + fm;
                af[mt] = *(const short8*)&Asc[((m << 3) | (kg ^ (m & 7))) << 3];
            }
            #pragma unroll
            for (int mt = 0; mt < 4; ++mt)
                #pragma unroll
                for (int nt = 0; nt < 4; ++nt)
                    acc[mt][nt] = __builtin_amdgcn_mfma_f32_16x16x32_bf16(
                        af[mt], bfr[nt], acc[mt][nt], 0, 0, 0);
        }
        // single light barrier: publishes As[c^1], protects As[c] overwrite.
        // No global_load_lds anywhere -> the implicit vmcnt(0) here is free
        // (all B loads already consumed by this step's MFMAs).
        __syncthreads();
    }

    // ---- epilogue: C layout col=lane&15, row=(lane>>4)*4+reg ; add base_b
    const int rq = fq << 2;
    float bias[4];
    #pragma unroll
    for (int nt = 0; nt < 4; ++nt) bias[nt] = bb[wn + (nt << 4) + fm];
    #pragma unroll
    for (int mt = 0; mt < 4; ++mt) {
        #pragma unroll
        for (int nt = 0; nt < 4; ++nt) {
            const int gr = n0 + wm + (mt << 4) + rq;
            const int gc = wn + (nt << 4) + fm;
            #pragma unroll
            for (int r = 0; r < 4; ++r)
                out[(size_t)(gr + r) * DIM + gc] = acc[mt][nt][r] + bias[nt];
        }
    }
}

extern "C" void kernel_launch(void* const* d_in, const int* in_sizes, int n_in,
                              void* d_out, int out_size, void* d_ws, size_t ws_size,
                              hipStream_t stream) {
    const float* x   = (const float*)d_in[0];
    const float* gam = (const float*)d_in[1];
    const float* bet = (const float*)d_in[2];
    const float* sw  = (const float*)d_in[3];
    const float* bwt = (const float*)d_in[4];
    const float* bb  = (const float*)d_in[5];
    float* out = (float*)d_out;

    unsigned short* Bw = (unsigned short*)d_ws;   // 512*8192 bf16 = 8 MB

    prep_w_k<<<dim3(512), dim3(256), 0, stream>>>(sw, bwt, Bw);
    kan_gemm<<<dim3(256), dim3(1024), 0, stream>>>(x, Bw, gam, bet, bb, out);
}

// Round 6
// 584.129 us; speedup vs baseline: 1.1207x; 1.1207x over previous
//
#include <hip/hip_runtime.h>
#include <hip/hip_bf16.h>
#include <stdint.h>

typedef __attribute__((ext_vector_type(8))) short short8;
typedef __attribute__((ext_vector_type(4))) float f32x4;
typedef __attribute__((ext_vector_type(4))) unsigned int u32x4;

#define NROWS 32768
#define DIM 512
#define KTOT 8192
#define KSPL 7680
#define LNEPS 1e-3f
// q = SQL * xn ; basis = exp2(-(q - SQL*grid_g)^2) ; SQL = 3.5*sqrt(log2(e))
#define SQL 4.20392843f

#if __has_builtin(__builtin_amdgcn_exp2f)
#define EXP2F(x) __builtin_amdgcn_exp2f(x)
#else
#define EXP2F(x) exp2f(x)
#endif

__device__ __forceinline__ unsigned short f2bf(float f) {
    unsigned u = __float_as_uint(f);
    u += 0x7fffu + ((u >> 16) & 1u);           // RNE
    return (unsigned short)(u >> 16);
}

// pack two floats -> two bf16 (round-half-up) in one u32 via v_perm
__device__ __forceinline__ unsigned pack_bf2(float a, float b) {
    unsigned ua = __float_as_uint(a) + 0x8000u;
    unsigned ub = __float_as_uint(b) + 0x8000u;
    return __builtin_amdgcn_perm(ub, ua, 0x07060302u); // lo16=ua>>16, hi16=ub>>16
}

// ---------------- prep: weights -> bf16 Bw[o][k_new].
// k_new = dsb*1024 + j*128 + glo*64 + dlo  maps to (g = 2j+glo, d = dsb*64+dlo);
// the (j=7, glo=1) slot holds base_w^T (relu path). This pairs grids (2j,2j+1)
// over the SAME 64-d range so a 128-wide k-step needs one q[8] per thread.
// Coalesced global reads AND writes; transpose via LDS (stride-15 reads).
__global__ __launch_bounds__(256) void prep_w_k(const float* __restrict__ sw,
                                                const float* __restrict__ bwt,
                                                unsigned short* __restrict__ Bw) {
    __shared__ float lds[KTOT];                 // 7680 spline + 512 base
    const int o = blockIdx.x;
    const int t = threadIdx.x;
    const float* swr = sw + (size_t)o * KSPL;
    unsigned short* br = Bw + (size_t)o * KTOT;
    #pragma unroll
    for (int it = 0; it < 30; ++it) lds[it * 256 + t] = swr[it * 256 + t];
    #pragma unroll
    for (int it = 0; it < 2; ++it) {
        int d = it * 256 + t;
        lds[KSPL + d] = bwt[(size_t)d * DIM + o];
    }
    __syncthreads();
    #pragma unroll
    for (int it = 0; it < 32; ++it) {
        int k = it * 256 + t;
        int dsb = k >> 10, r = k & 1023;
        int j = r >> 7, glo = (r >> 6) & 1, dlo = r & 63;
        int g = 2 * j + glo, d = (dsb << 6) + dlo;
        float v = (g < 15) ? lds[d * 15 + g] : lds[KSPL + d];
        br[k] = f2bf(v);
    }
}

// ---------------- fused LN + KAN GEMM: out[n][o] = sum_k A[n][k]*Bw[o][k] + bb[o]
// Same 2-barrier skeleton as the 314us baseline (stage -> sync -> MFMA -> sync),
// with BK 64 -> 128: 64 k-steps instead of 128, halving per-step fixed costs
// (barrier crossings + DMA-residual drain) while total MFMA/LDS/VALU work is
// unchanged. Block tile 128x512, 1024 thr (16 waves, wave 64x64). LDS 160KB
// (As 32KB + Bs 128KB, single-buffered). Grid 256 = 1 block/CU (VGPR-bound).
__global__ __launch_bounds__(1024, 4) void kan_gemm(
    const float* __restrict__ x,
    const unsigned short* __restrict__ Bw,
    const float* __restrict__ gam,
    const float* __restrict__ bet,
    const float* __restrict__ bb,
    float* __restrict__ out) {
    __shared__ __align__(16) short As[128 * 128];   // 32 KB
    __shared__ __align__(16) short Bs[512 * 128];   // 128 KB

    const int t = threadIdx.x;
    const int w = t >> 6, l = t & 63;
    const int n0 = blockIdx.x << 7;

    const int ar  = t >> 3;    // A-staging row 0..127 (also LN-stats row)
    const int kkg = t & 7;     // A-staging d-granule
    const int wm = (w >> 3) << 6;            // wave row offset: 0 / 64
    const int wn = (w & 7) << 6;             // wave col offset: 0..448
    const int fm = l & 15, fq = l >> 4;
    const int brow4 = l >> 4;                // B-DMA row-in-4
    const int g16 = l & 15;                  // B-DMA dest granule
    const int sgA = kkg ^ (ar & 7);          // A-store swizzled low-granule

    // ---- LayerNorm stats for row ar (8 threads/row, shuffle reduce)
    const float* xrow = x + (size_t)(n0 + ar) * DIM;
    float s = 0.f, ss = 0.f;
    #pragma unroll
    for (int it = 0; it < 16; ++it) {
        float4 v = *(const float4*)(xrow + it * 32 + ((t & 7) << 2));
        s  += v.x + v.y + v.z + v.w;
        ss += v.x * v.x + v.y * v.y + v.z * v.z + v.w * v.w;
    }
    #pragma unroll
    for (int m = 4; m >= 1; m >>= 1) {
        s  += __shfl_xor(s,  m, 64);
        ss += __shfl_xor(ss, m, 64);
    }
    const float mean = s * (1.0f / DIM);
    const float rstd = rsqrtf(ss * (1.0f / DIM) - mean * mean + LNEPS);
    const float sr = SQL * rstd;

    f32x4 acc[4][4];
    #pragma unroll
    for (int i = 0; i < 4; ++i)
        #pragma unroll
        for (int j = 0; j < 4; ++j)
            acc[i][j] = (f32x4)0.0f;

    #pragma unroll 1
    for (int dsb = 0; dsb < 8; ++dsb) {
        const int d0 = dsb << 6;
        const int dc = d0 + (kkg << 3);
        // raw x slice (reused for relu) and pre-scaled q = SQL*layernorm(x)
        float xr[8], q[8];
        {
            float4 a = *(const float4*)(xrow + dc);
            float4 b = *(const float4*)(xrow + dc + 4);
            xr[0] = a.x; xr[1] = a.y; xr[2] = a.z; xr[3] = a.w;
            xr[4] = b.x; xr[5] = b.y; xr[6] = b.z; xr[7] = b.w;
            float4 g0 = *(const float4*)(gam + dc);
            float4 g1 = *(const float4*)(gam + dc + 4);
            float4 b0 = *(const float4*)(bet + dc);
            float4 b1 = *(const float4*)(bet + dc + 4);
            float gv[8] = {g0.x, g0.y, g0.z, g0.w, g1.x, g1.y, g1.z, g1.w};
            float bv[8] = {b0.x, b0.y, b0.z, b0.w, b1.x, b1.y, b1.z, b1.w};
            #pragma unroll
            for (int j = 0; j < 8; ++j) {
                float c = sr * gv[j];
                float o = __builtin_fmaf(-mean, c, SQL * bv[j]);
                q[j] = __builtin_fmaf(xr[j], c, o);
            }
        }
        #pragma unroll 1
        for (int j = 0; j < 8; ++j) {
            const int kc = (dsb << 10) + (j << 7);    // k_new step base
            // ---- B staging: 512x128 bf16 (128KB) via async DMA, 8 instr/thread.
            // Dest is linear [row][granule]; xor swizzle realized by permuting
            // the per-lane GLOBAL source granule (dest gran g16 <- src gran
            // (g16&8)|((g16^(row&7))&7), an involution).
            #pragma unroll
            for (int i = 0; i < 8; ++i) {
                const int rb = (w << 5) + (i << 2);   // wave-uniform, 4 rows/instr
                const int row = rb + brow4;
                const int srcg = (g16 & 8) | ((g16 ^ (row & 7)) & 7);
                const unsigned short* gp =
                    Bw + (size_t)row * KTOT + kc + (srcg << 3);
                __builtin_amdgcn_global_load_lds(
                    (const __attribute__((address_space(1))) void*)gp,
                    (__attribute__((address_space(3))) void*)&Bs[rb << 7],
                    16, 0, 0);
            }
            // ---- A staging: pair (g=2j, g=2j+1) basis (or relu at j=7,glo=1)
            // from the same q[8]; two u32x4 stores, xor-swizzled.
            {
                const float qg0 = SQL * (-2.0f + (float)(2 * j) * (2.0f / 7.0f));
                float e[8];
                #pragma unroll
                for (int jj = 0; jj < 8; ++jj) {
                    float d = q[jj] - qg0;
                    e[jj] = EXP2F(-(d * d));
                }
                u32x4 v;
                v[0] = pack_bf2(e[0], e[1]);
                v[1] = pack_bf2(e[2], e[3]);
                v[2] = pack_bf2(e[4], e[5]);
                v[3] = pack_bf2(e[6], e[7]);
                *(u32x4*)&As[(ar << 7) + (sgA << 3)] = v;
            }
            {
                u32x4 v;
                if (j < 7) {
                    const float qg1 = SQL * (-2.0f + (float)(2 * j + 1) * (2.0f / 7.0f));
                    float e[8];
                    #pragma unroll
                    for (int jj = 0; jj < 8; ++jj) {
                        float d = q[jj] - qg1;
                        e[jj] = EXP2F(-(d * d));
                    }
                    v[0] = pack_bf2(e[0], e[1]);
                    v[1] = pack_bf2(e[2], e[3]);
                    v[2] = pack_bf2(e[4], e[5]);
                    v[3] = pack_bf2(e[6], e[7]);
                } else {
                    v[0] = pack_bf2(fmaxf(xr[0], 0.f), fmaxf(xr[1], 0.f));
                    v[1] = pack_bf2(fmaxf(xr[2], 0.f), fmaxf(xr[3], 0.f));
                    v[2] = pack_bf2(fmaxf(xr[4], 0.f), fmaxf(xr[5], 0.f));
                    v[3] = pack_bf2(fmaxf(xr[6], 0.f), fmaxf(xr[7], 0.f));
                }
                *(u32x4*)&As[(ar << 7) + 64 + (sgA << 3)] = v;
            }
            __syncthreads();
            // ---- MFMA: 4 k-steps of 32, 4x4 tiles of 16x16 (wave 64x64)
            #pragma unroll
            for (int ks = 0; ks < 4; ++ks) {
                const int kg = (ks << 2) + fq;
                short8 af[4], bfr[4];
                #pragma unroll
                for (int mt = 0; mt < 4; ++mt) {
                    const int m = wm + (mt << 4) + fm;
                    const int gA = (kg & 8) | ((kg ^ (m & 7)) & 7);
                    af[mt] = *(const short8*)&As[(m << 7) + (gA << 3)];
                }
                #pragma unroll
                for (int nt = 0; nt < 4; ++nt) {
                    const int n = wn + (nt << 4) + fm;
                    const int gB = (kg & 8) | ((kg ^ (n & 7)) & 7);
                    bfr[nt] = *(const short8*)&Bs[(n << 7) + (gB << 3)];
                }
                #pragma unroll
                for (int mt = 0; mt < 4; ++mt)
                    #pragma unroll
                    for (int nt = 0; nt < 4; ++nt)
                        acc[mt][nt] = __builtin_amdgcn_mfma_f32_16x16x32_bf16(
                            af[mt], bfr[nt], acc[mt][nt], 0, 0, 0);
            }
            __syncthreads();
        }
    }
    // ---- epilogue: C layout col=lane&15, row=(lane>>4)*4+reg ; add base_b
    const int rq = fq << 2;
    float bias[4];
    #pragma unroll
    for (int nt = 0; nt < 4; ++nt) bias[nt] = bb[wn + (nt << 4) + fm];
    #pragma unroll
    for (int mt = 0; mt < 4; ++mt) {
        #pragma unroll
        for (int nt = 0; nt < 4; ++nt) {
            const int gr = n0 + wm + (mt << 4) + rq;
            const int gc = wn + (nt << 4) + fm;
            #pragma unroll
            for (int r = 0; r < 4; ++r)
                out[(size_t)(gr + r) * DIM + gc] = acc[mt][nt][r] + bias[nt];
        }
    }
}

extern "C" void kernel_launch(void* const* d_in, const int* in_sizes, int n_in,
                              void* d_out, int out_size, void* d_ws, size_t ws_size,
                              hipStream_t stream) {
    const float* x   = (const float*)d_in[0];
    const float* gam = (const float*)d_in[1];
    const float* bet = (const float*)d_in[2];
    const float* sw  = (const float*)d_in[3];
    const float* bwt = (const float*)d_in[4];
    const float* bb  = (const float*)d_in[5];
    float* out = (float*)d_out;

    unsigned short* Bw = (unsigned short*)d_ws;   // 512*8192 bf16 = 8 MB

    prep_w_k<<<dim3(512), dim3(256), 0, stream>>>(sw, bwt, Bw);
    kan_gemm<<<dim3(256), dim3(1024), 0, stream>>>(x, Bw, gam, bet, bb, out);
}